// Round 1
// baseline (616.184 us; speedup 1.0000x reference)
//
#include <hip/hip_runtime.h>
#include <hip/hip_bf16.h>

// ---------------------------------------------------------------------------
// Axis_Portrait_Attention: B=4, C=Cr=256, H=W=128, HW=16384
// outputs (fp32, concat): out_w[4,256,128,128], x_Qw[4,128,32768],
//                         x_Kw[4,32768,128],  x_Vw[4,32768,128],
//                         gamma[1], attn[4,128,128]
// Key facts: x_Qw == contiguous relu(conv) output; x_Kw/x_Vw are its
// [128,32768] -> [32768,128] transpose (i = c>>1, j = (c&1)*16384 + h*128 + w).
// Q/K conv and QK^T use split-bf16 (hi+lo) 3-pass MFMA for fp32-like logits
// (softmax over huge logits is sensitive); V / PV / final conv use plain bf16.
// ---------------------------------------------------------------------------

typedef __attribute__((ext_vector_type(8))) short bf16x8;   // 8 bf16 (4 VGPR)
typedef __attribute__((ext_vector_type(4))) float f4;       // MFMA C/D

#define MFMA16(a, b, c) __builtin_amdgcn_mfma_f32_16x16x32_bf16(a, b, c, 0, 0, 0)

__device__ __forceinline__ unsigned short f2bf(float f) {  // RNE
  union { float f; unsigned u; } v; v.f = f;
  unsigned r = v.u + 0x7fffu + ((v.u >> 16) & 1u);
  return (unsigned short)(r >> 16);
}
__device__ __forceinline__ float bf2f(unsigned short h) {
  union { unsigned u; float f; } v; v.u = ((unsigned)h) << 16;
  return v.f;
}
__device__ __forceinline__ void splitf(float f, unsigned short &hi, unsigned short &lo) {
  unsigned short h = f2bf(f);
  hi = h; lo = f2bf(f - bf2f(h));
}

// truncation split of 8 floats -> hi/lo bf16x8 using v_perm packing (cheap).
// (hi = top16 bits; lo = bf16(f - hi); product err ~2^-16 rel, plenty.)
__device__ __forceinline__ void split8t(float4 a, float4 b, bf16x8 &hi, bf16x8 &lo) {
  union { bf16x8 v; unsigned u[4]; } uh, ul;
  const unsigned* ua = (const unsigned*)&a;
  const unsigned* ub = (const unsigned*)&b;
  const float* fa = (const float*)&a;
  const float* fb = (const float*)&b;
#pragma unroll
  for (int e = 0; e < 2; ++e) {
    uh.u[e]     = __builtin_amdgcn_perm(ua[2*e+1], ua[2*e], 0x07060302u);
    uh.u[2 + e] = __builtin_amdgcn_perm(ub[2*e+1], ub[2*e], 0x07060302u);
    union { float f; unsigned u; } p0, p1, q0, q1;
    p0.u = ua[2*e] & 0xffff0000u;   p1.u = ua[2*e+1] & 0xffff0000u;
    p0.f = fa[2*e] - p0.f;          p1.f = fa[2*e+1] - p1.f;
    ul.u[e] = __builtin_amdgcn_perm(p1.u, p0.u, 0x07060302u);
    q0.u = ub[2*e] & 0xffff0000u;   q1.u = ub[2*e+1] & 0xffff0000u;
    q0.f = fb[2*e] - q0.f;          q1.f = fb[2*e+1] - q1.f;
    ul.u[2 + e] = __builtin_amdgcn_perm(q1.u, q0.u, 0x07060302u);
  }
  hi = uh.v; lo = ul.v;
}

// truncation-pack 8 floats -> bf16x8 (4 v_perm)
__device__ __forceinline__ bf16x8 pack8t(float4 a, float4 b) {
  union { bf16x8 v; unsigned u[4]; } r;
  const unsigned* ua = (const unsigned*)&a;
  const unsigned* ub = (const unsigned*)&b;
  r.u[0] = __builtin_amdgcn_perm(ua[1], ua[0], 0x07060302u);
  r.u[1] = __builtin_amdgcn_perm(ua[3], ua[2], 0x07060302u);
  r.u[2] = __builtin_amdgcn_perm(ub[1], ub[0], 0x07060302u);
  r.u[3] = __builtin_amdgcn_perm(ub[3], ub[2], 0x07060302u);
  return r.v;
}

// ---------------------------------------------------------------------------
// K0: precompute weight splits (reused by all 1024 conv blocks)
// ---------------------------------------------------------------------------
__global__ __launch_bounds__(256) void k_prep(
    const float* __restrict__ Wq, const float* __restrict__ Wk,
    const float* __restrict__ Wv, const float* __restrict__ Wu,
    unsigned short* __restrict__ wqh, unsigned short* __restrict__ wql,
    unsigned short* __restrict__ wkh, unsigned short* __restrict__ wkl,
    unsigned short* __restrict__ wvh, unsigned short* __restrict__ wuh) {
  const int i = blockIdx.x * 256 + threadIdx.x;  // 65536 total
  unsigned short h, lo2;
  splitf(Wq[i], h, lo2); wqh[i] = h; wql[i] = lo2;
  splitf(Wk[i], h, lo2); wkh[i] = h; wkl[i] = lo2;
  wvh[i] = f2bf(Wv[i]);
  wuh[i] = f2bf(Wu[i]);
}

// ---------------------------------------------------------------------------
// K1: fused QKV 1x1 conv.  Per block: all 256 out-channels x 64 hw positions.
// Stages x tile transposed (hi/lo bf16) in LDS; Q written contiguous to d_out;
// K written contiguous to ws (for QK^T) + transposed to x_Kw; V transposed to
// x_Vw.  Transposed writes routed through a 32KB LDS buffer (512B row stores).
// ---------------------------------------------------------------------------
__global__ __launch_bounds__(256) void k_qkv(
    const float* __restrict__ x,
    const unsigned short* __restrict__ wqh, const unsigned short* __restrict__ wql,
    const unsigned short* __restrict__ wkh, const unsigned short* __restrict__ wkl,
    const unsigned short* __restrict__ wvh,
    const float* __restrict__ bq, const float* __restrict__ bk,
    const float* __restrict__ bv,
    float* __restrict__ outQ, float* __restrict__ outKT, float* __restrict__ outVT,
    float* __restrict__ K2f, float* __restrict__ Sbuf) {
  const int pb = blockIdx.x, b = blockIdx.y;
  const int p0 = pb * 64;
  const int t = threadIdx.x;

  // zero the logit accumulator for k_qk's atomics (4 blocks do it)
  if (pb == 0)
    for (int i = t; i < 16384; i += 256) Sbuf[b * 16384 + i] = 0.0f;

  __shared__ unsigned short xthi[64][264];  // [p][c], pad 8 -> row 528B
  __shared__ unsigned short xtlo[64][264];
  __shared__ float tbuf[64][132];           // transpose-out buffer [p][i]

  {  // stage x[b, :, p0..p0+63] transposed + split
    const int cp = t & 127;          // channel pair 2cp, 2cp+1
    const int ph = (t >> 7) * 32;    // p-half
    const float* r0 = x + ((size_t)b * 256 + 2 * cp) * 16384 + p0 + ph;
    const float* r1 = r0 + 16384;
#pragma unroll
    for (int q = 0; q < 8; ++q) {
      float4 v0 = *(const float4*)(r0 + 4 * q);
      float4 v1 = *(const float4*)(r1 + 4 * q);
      const unsigned* u0 = (const unsigned*)&v0;
      const unsigned* u1 = (const unsigned*)&v1;
      const float* f0 = (const float*)&v0;
      const float* f1 = (const float*)&v1;
#pragma unroll
      for (int e = 0; e < 4; ++e) {
        const int p = ph + 4 * q + e;
        *(unsigned*)&xthi[p][2 * cp] = __builtin_amdgcn_perm(u1[e], u0[e], 0x07060302u);
        union { float f; unsigned u; } l0, l1;
        l0.u = u0[e] & 0xffff0000u;  l1.u = u1[e] & 0xffff0000u;
        l0.f = f0[e] - l0.f;         l1.f = f1[e] - l1.f;
        *(unsigned*)&xtlo[p][2 * cp] = __builtin_amdgcn_perm(l1.u, l0.u, 0x07060302u);
      }
    }
  }
  __syncthreads();

  const int wv = t >> 6, l = t & 63;
  const int lr = l & 15, lkq = l >> 4, lk = lkq * 8;
  const size_t ob = (size_t)b * 4194304;
  const f4 fz = {0.f, 0.f, 0.f, 0.f};
  f4 acc[4][4];

#define CONV_PASS(WHI, WLO, SPLIT)                                        \
  {                                                                       \
    _Pragma("unroll") for (int mt = 0; mt < 4; ++mt)                      \
    _Pragma("unroll") for (int nt = 0; nt < 4; ++nt) acc[mt][nt] = fz;    \
    _Pragma("unroll 1") for (int kk = 0; kk < 8; ++kk) {                  \
      const int c0 = kk * 32 + lk;                                        \
      bf16x8 ahi[4], alo[4], bhi[4], blo[4];                              \
      _Pragma("unroll") for (int mt = 0; mt < 4; ++mt) {                  \
        const int o = wv * 64 + mt * 16 + lr;                             \
        ahi[mt] = *(const bf16x8*)(WHI + o * 256 + c0);                   \
        if (SPLIT) alo[mt] = *(const bf16x8*)(WLO + o * 256 + c0);        \
      }                                                                   \
      _Pragma("unroll") for (int nt = 0; nt < 4; ++nt) {                  \
        bhi[nt] = *(const bf16x8*)&xthi[nt * 16 + lr][c0];                \
        if (SPLIT) blo[nt] = *(const bf16x8*)&xtlo[nt * 16 + lr][c0];     \
      }                                                                   \
      _Pragma("unroll") for (int mt = 0; mt < 4; ++mt)                    \
      _Pragma("unroll") for (int nt = 0; nt < 4; ++nt) {                  \
        acc[mt][nt] = MFMA16(ahi[mt], bhi[nt], acc[mt][nt]);              \
        if (SPLIT) {                                                      \
          acc[mt][nt] = MFMA16(ahi[mt], blo[nt], acc[mt][nt]);            \
          acc[mt][nt] = MFMA16(alo[mt], bhi[nt], acc[mt][nt]);            \
        }                                                                 \
      }                                                                   \
    }                                                                     \
  }

  // LDS transpose-out: writes rows  x_?w[b, par*16384 + p_global, 0..127]
#define TRANSPOSE_OUT(DST)                                                   \
  _Pragma("unroll") for (int par = 0; par < 2; ++par) {                      \
    __syncthreads();                                                         \
    const int ibase = wv * 32 + lkq * 2;                                     \
    _Pragma("unroll") for (int mt = 0; mt < 4; ++mt)                         \
    _Pragma("unroll") for (int m = 0; m < 2; ++m) {                          \
      const int i = ibase + mt * 8 + m;                                      \
      const int e = par + 2 * m; /* o parity == e parity (base even) */      \
      _Pragma("unroll") for (int nt = 0; nt < 4; ++nt)                       \
        tbuf[nt * 16 + lr][i] = acc[mt][nt][e];                              \
    }                                                                        \
    __syncthreads();                                                         \
    {                                                                        \
      const int pr = t >> 2, seg = (t & 3) * 32;                             \
      float* dst = DST + ob + (size_t)(par * 16384 + p0 + pr) * 128 + seg;   \
      _Pragma("unroll") for (int q2 = 0; q2 < 8; ++q2)                       \
        *(float4*)(dst + 4 * q2) = *(const float4*)&tbuf[pr][seg + 4 * q2];  \
    }                                                                        \
  }

  // ---------------- Q (split precision, contiguous out) ----------------
  CONV_PASS(wqh, wql, 1)
  {
    const int rbase = wv * 64 + lkq * 4;
#pragma unroll
    for (int mt = 0; mt < 4; ++mt)
#pragma unroll
      for (int e = 0; e < 4; ++e) {
        const int o = rbase + mt * 16 + e;
        const float bb = bq[o];
#pragma unroll
        for (int nt = 0; nt < 4; ++nt)
          outQ[ob + (size_t)o * 16384 + (p0 + nt * 16 + lr)] =
              fmaxf(acc[mt][nt][e] + bb, 0.0f);
      }
  }

  // ---------------- K (split; contiguous ws copy + transposed) ----------
  CONV_PASS(wkh, wkl, 1)
  {
    const int rbase = wv * 64 + lkq * 4;
#pragma unroll
    for (int mt = 0; mt < 4; ++mt)
#pragma unroll
      for (int e = 0; e < 4; ++e) {
        const int o = rbase + mt * 16 + e;
        const float bb = bk[o];
#pragma unroll
        for (int nt = 0; nt < 4; ++nt) {
          const float v = fmaxf(acc[mt][nt][e] + bb, 0.0f);
          acc[mt][nt][e] = v;
          K2f[ob + (size_t)o * 16384 + (p0 + nt * 16 + lr)] = v;
        }
      }
  }
  TRANSPOSE_OUT(outKT)

  // ---------------- V (plain bf16; transposed only) ---------------------
  CONV_PASS(wvh, wvh, 0)
  {
    const int rbase = wv * 64 + lkq * 4;
#pragma unroll
    for (int mt = 0; mt < 4; ++mt)
#pragma unroll
      for (int e = 0; e < 4; ++e) {
        const int o = rbase + mt * 16 + e;
        const float bb = bv[o];
#pragma unroll
        for (int nt = 0; nt < 4; ++nt)
          acc[mt][nt][e] = fmaxf(acc[mt][nt][e] + bb, 0.0f);
      }
  }
  TRANSPOSE_OUT(outVT)
#undef CONV_PASS
#undef TRANSPOSE_OUT
}

// ---------------------------------------------------------------------------
// K2: S = Q2 @ K2^T  (split-K over j, 32 splits; split-bf16 3-pass MFMA;
// fp32 atomicAdd into Sbuf).  Lane quartets cover full 128B lines.
// ---------------------------------------------------------------------------
__global__ __launch_bounds__(256) void k_qk(
    const float* __restrict__ Q2, const float* __restrict__ K2f,
    float* __restrict__ Sbuf) {
  const int s = blockIdx.x, b = blockIdx.y;
  const int t = threadIdx.x;
  const int wvv = t >> 6, l = t & 63;
  const int wm = (wvv >> 1) * 64, wn = (wvv & 1) * 64;
  const int lr = l & 15, lkq = l >> 4, lk = lkq * 8;
  const size_t qb = (size_t)b * 4194304;
  const int jb = s * 1024;
  const f4 fz = {0.f, 0.f, 0.f, 0.f};
  f4 acc[4][4];
#pragma unroll
  for (int mt = 0; mt < 4; ++mt)
#pragma unroll
    for (int nt = 0; nt < 4; ++nt) acc[mt][nt] = fz;

#pragma unroll 1
  for (int kk = 0; kk < 32; ++kk) {
    const int j = jb + kk * 32 + lk;
    bf16x8 ahi[4], alo[4], bhi[4], blo[4];
#pragma unroll
    for (int mt = 0; mt < 4; ++mt) {
      const float* r = Q2 + qb + (size_t)(wm + mt * 16 + lr) * 32768 + j;
      split8t(*(const float4*)r, *(const float4*)(r + 4), ahi[mt], alo[mt]);
    }
#pragma unroll
    for (int nt = 0; nt < 4; ++nt) {
      const float* r = K2f + qb + (size_t)(wn + nt * 16 + lr) * 32768 + j;
      split8t(*(const float4*)r, *(const float4*)(r + 4), bhi[nt], blo[nt]);
    }
#pragma unroll
    for (int mt = 0; mt < 4; ++mt)
#pragma unroll
      for (int nt = 0; nt < 4; ++nt) {
        acc[mt][nt] = MFMA16(ahi[mt], bhi[nt], acc[mt][nt]);
        acc[mt][nt] = MFMA16(ahi[mt], blo[nt], acc[mt][nt]);
        acc[mt][nt] = MFMA16(alo[mt], bhi[nt], acc[mt][nt]);
      }
  }
#pragma unroll
  for (int mt = 0; mt < 4; ++mt)
#pragma unroll
    for (int e = 0; e < 4; ++e) {
      const int i1 = wm + mt * 16 + lkq * 4 + e;
#pragma unroll
      for (int nt = 0; nt < 4; ++nt) {
        const int i2 = wn + nt * 16 + lr;
        atomicAdd(&Sbuf[b * 16384 + i1 * 128 + i2], acc[mt][nt][e]);
      }
    }
}

// ---------------------------------------------------------------------------
// K3: softmax over axis i1 (per column i2); writes attn fp32 to d_out,
// gamma-folded bf16 attn^T to ws, and gamma scalar to d_out.
// ---------------------------------------------------------------------------
__global__ __launch_bounds__(256) void k_softmax(
    const float* __restrict__ Sbuf, const float* __restrict__ gin,
    float* __restrict__ attnO, float* __restrict__ gammaO,
    unsigned short* __restrict__ attnTg) {
  const int ch = blockIdx.x, b = blockIdx.y;
  const int t = threadIdx.x;
  const int col = t & 31, part = t >> 5;  // 8 parts x 16 rows
  const int cbase = ch * 32;
  __shared__ float sc[128][33];
  __shared__ float redA[8][33];
  __shared__ float redB[8][33];
#pragma unroll
  for (int rr = 0; rr < 16; ++rr) {
    const int i1 = part * 16 + rr;
    sc[i1][col] = Sbuf[b * 16384 + i1 * 128 + cbase + col];
  }
  __syncthreads();
  float mx = -3.4e38f;
#pragma unroll
  for (int rr = 0; rr < 16; ++rr) mx = fmaxf(mx, sc[part * 16 + rr][col]);
  redA[part][col] = mx;
  __syncthreads();
  if (part == 0) {
    float m2 = redA[0][col];
#pragma unroll
    for (int pp = 1; pp < 8; ++pp) m2 = fmaxf(m2, redA[pp][col]);
    redA[0][col] = m2;
  }
  __syncthreads();
  const float m = redA[0][col];
  float sum = 0.f;
#pragma unroll
  for (int rr = 0; rr < 16; ++rr) {
    const int i1 = part * 16 + rr;
    const float e = expf(sc[i1][col] - m);
    sc[i1][col] = e;
    sum += e;
  }
  redB[part][col] = sum;
  __syncthreads();
  if (part == 0) {
    float s2 = 0.f;
#pragma unroll
    for (int pp = 0; pp < 8; ++pp) s2 += redB[pp][col];
    redB[0][col] = 1.0f / s2;
  }
  __syncthreads();
  const float inv = redB[0][col];
  const float g = gin[0];
#pragma unroll
  for (int rr = 0; rr < 16; ++rr) {
    const int i1 = part * 16 + rr;
    const float v = sc[i1][col] * inv;
    attnO[b * 16384 + i1 * 128 + cbase + col] = v;
    attnTg[(size_t)b * 16384 + (size_t)(cbase + col) * 128 + i1] = f2bf(v * g);
  }
  if (b == 0 && ch == 0 && t == 0) gammaO[0] = gin[0];
}

// ---------------------------------------------------------------------------
// K4: out1 = V^T @ attn  (M=32768, N=128, K=128 per batch), gamma folded in
// attnTg.  A rows read straight from x_Vw (contiguous 512B rows).
// Output = gamma*out1 as bf16 'out' tensor [B,C,HW] (flat == j*128+i2).
// ---------------------------------------------------------------------------
__global__ __launch_bounds__(256) void k_pv(
    const float* __restrict__ VT, const unsigned short* __restrict__ attnTg,
    unsigned short* __restrict__ outb) {
  const int jblk = blockIdx.x, b = blockIdx.y;
  const int t = threadIdx.x;
  const int wvv = t >> 6, l = t & 63;
  const int lr = l & 15, lkq = l >> 4, lk = lkq * 8;
  const size_t vb = (size_t)b * 4194304;
  const int j0 = jblk * 256 + wvv * 64;
  const f4 fz = {0.f, 0.f, 0.f, 0.f};
  f4 acc[4][8];
#pragma unroll
  for (int mt = 0; mt < 4; ++mt)
#pragma unroll
    for (int nt = 0; nt < 8; ++nt) acc[mt][nt] = fz;

#pragma unroll
  for (int kk = 0; kk < 4; ++kk) {
    const int k0 = kk * 32 + lk;
    bf16x8 av[4], bt[8];
#pragma unroll
    for (int mt = 0; mt < 4; ++mt) {
      const float* r = VT + vb + (size_t)(j0 + mt * 16 + lr) * 128 + k0;
      av[mt] = pack8t(*(const float4*)r, *(const float4*)(r + 4));
    }
#pragma unroll
    for (int nt = 0; nt < 8; ++nt)
      bt[nt] = *(const bf16x8*)(attnTg + (size_t)b * 16384 +
                                (size_t)(nt * 16 + lr) * 128 + k0);
#pragma unroll
    for (int mt = 0; mt < 4; ++mt)
#pragma unroll
      for (int nt = 0; nt < 8; ++nt)
        acc[mt][nt] = MFMA16(av[mt], bt[nt], acc[mt][nt]);
  }
#pragma unroll
  for (int mt = 0; mt < 4; ++mt)
#pragma unroll
    for (int e = 0; e < 4; ++e) {
      const int j = j0 + mt * 16 + lkq * 4 + e;
#pragma unroll
      for (int nt = 0; nt < 8; ++nt)
        outb[vb + (size_t)j * 128 + (nt * 16 + lr)] = f2bf(acc[mt][nt][e]);
    }
}

// ---------------------------------------------------------------------------
// K5: out_w = Wu @ out + bu  (no relu), plain bf16 MFMA, fp32 out to d_out.
// ---------------------------------------------------------------------------
__global__ __launch_bounds__(256) void k_up(
    const unsigned short* __restrict__ outb, const unsigned short* __restrict__ wuh,
    const float* __restrict__ bu, float* __restrict__ outw) {
  const int pb = blockIdx.x, b = blockIdx.y;
  const int p0 = pb * 64;
  const int t = threadIdx.x;
  __shared__ unsigned short ot[64][264];
  {
    const int cp = t & 127;
    const int ph = (t >> 7) * 32;
    const unsigned short* row0 = outb + ((size_t)b * 256 + 2 * cp) * 16384 + p0 + ph;
    const unsigned* r0 = (const unsigned*)row0;
    const unsigned* r1 = (const unsigned*)(row0 + 16384);
#pragma unroll
    for (int k = 0; k < 16; ++k) {
      const unsigned a0 = r0[k], a1 = r1[k];
      const int p = ph + 2 * k;
      *(unsigned*)&ot[p][2 * cp] = (a0 & 0xffffu) | (a1 << 16);
      *(unsigned*)&ot[p + 1][2 * cp] = (a0 >> 16) | (a1 & 0xffff0000u);
    }
  }
  __syncthreads();
  const int wv = t >> 6, l = t & 63;
  const int lr = l & 15, lkq = l >> 4, lk = lkq * 8;
  const f4 fz = {0.f, 0.f, 0.f, 0.f};
  f4 acc[4][4];
#pragma unroll
  for (int mt = 0; mt < 4; ++mt)
#pragma unroll
    for (int nt = 0; nt < 4; ++nt) acc[mt][nt] = fz;

#pragma unroll 1
  for (int kk = 0; kk < 8; ++kk) {
    const int c0 = kk * 32 + lk;
    bf16x8 a[4], bt[4];
#pragma unroll
    for (int mt = 0; mt < 4; ++mt)
      a[mt] = *(const bf16x8*)(wuh + (wv * 64 + mt * 16 + lr) * 256 + c0);
#pragma unroll
    for (int nt = 0; nt < 4; ++nt)
      bt[nt] = *(const bf16x8*)&ot[nt * 16 + lr][c0];
#pragma unroll
    for (int mt = 0; mt < 4; ++mt)
#pragma unroll
      for (int nt = 0; nt < 4; ++nt)
        acc[mt][nt] = MFMA16(a[mt], bt[nt], acc[mt][nt]);
  }
  const size_t ob2 = (size_t)b * 4194304;
  const int rbase = wv * 64 + lkq * 4;
#pragma unroll
  for (int mt = 0; mt < 4; ++mt)
#pragma unroll
    for (int e = 0; e < 4; ++e) {
      const int o = rbase + mt * 16 + e;
      const float bb = bu[o];
#pragma unroll
      for (int nt = 0; nt < 4; ++nt)
        outw[ob2 + (size_t)o * 16384 + (p0 + nt * 16 + lr)] = acc[mt][nt][e] + bb;
    }
}

// ---------------------------------------------------------------------------
extern "C" void kernel_launch(void* const* d_in, const int* in_sizes, int n_in,
                              void* d_out, int out_size, void* d_ws, size_t ws_size,
                              hipStream_t stream) {
  (void)in_sizes; (void)n_in; (void)out_size; (void)ws_size;
  const float* x  = (const float*)d_in[0];
  const float* Wq = (const float*)d_in[1];
  const float* bq = (const float*)d_in[2];
  const float* Wk = (const float*)d_in[3];
  const float* bk = (const float*)d_in[4];
  const float* Wv = (const float*)d_in[5];
  const float* bv = (const float*)d_in[6];
  const float* Wu = (const float*)d_in[7];
  const float* bu = (const float*)d_in[8];
  const float* gm = (const float*)d_in[9];

  float* dout   = (float*)d_out;
  float* outw   = dout;                 // [4,256,128,128]
  float* outQ   = dout + 16777216;      // x_Qw  (contiguous conv out)
  float* outKT  = dout + 33554432;      // x_Kw  (transposed)
  float* outVT  = dout + 50331648;      // x_Vw  (transposed)
  float* gammaO = dout + 67108864;      // gamma
  float* attnO  = dout + 67108865;      // attn [4,128,128]

  char* wsb = (char*)d_ws;
  float* K2f   = (float*)(wsb);                            // 64 MiB: K rows contiguous
  float* Sbuf  = (float*)(wsb + 67108864);                 // 256 KiB logits
  unsigned short* attnTg = (unsigned short*)(wsb + 67371008);  // 128 KiB attn^T * gamma
  unsigned short* outb   = (unsigned short*)(wsb + 67502080);  // 32 MiB bf16 'out'
  unsigned short* wqh = (unsigned short*)(wsb + 101056512);
  unsigned short* wql = wqh + 65536;
  unsigned short* wkh = wql + 65536;
  unsigned short* wkl = wkh + 65536;
  unsigned short* wvh = wkl + 65536;
  unsigned short* wuh = wvh + 65536;

  k_prep<<<dim3(256), dim3(256), 0, stream>>>(Wq, Wk, Wv, Wu,
                                              wqh, wql, wkh, wkl, wvh, wuh);
  k_qkv<<<dim3(256, 4), dim3(256), 0, stream>>>(x, wqh, wql, wkh, wkl, wvh,
                                                bq, bk, bv,
                                                outQ, outKT, outVT, K2f, Sbuf);
  k_qk<<<dim3(32, 4), dim3(256), 0, stream>>>(outQ, K2f, Sbuf);
  k_softmax<<<dim3(4, 4), dim3(256), 0, stream>>>(Sbuf, gm, attnO, gammaO, attnTg);
  k_pv<<<dim3(128, 4), dim3(256), 0, stream>>>(outVT, attnTg, outb);
  k_up<<<dim3(256, 4), dim3(256), 0, stream>>>(outb, wuh, bu, outw);
}

// Round 2
// 591.474 us; speedup vs baseline: 1.0418x; 1.0418x over previous
//
#include <hip/hip_runtime.h>
#include <hip/hip_bf16.h>

// ---------------------------------------------------------------------------
// Axis_Portrait_Attention: B=4, C=Cr=256, H=W=128, HW=16384
// outputs (fp32, concat): out_w[4,256,128,128], x_Qw[4,128,32768],
//                         x_Kw[4,32768,128],  x_Vw[4,32768,128],
//                         gamma[1], attn[4,128,128]
// x_Qw == contiguous relu(conv) output; x_Kw/x_Vw are its transpose.
// Q/K conv and QK^T use split-bf16 (hi+lo) 3-pass MFMA; V/PV/up-conv plain bf16.
// Round 2: occupancy attack. k_qkv 32-pos tile + tbuf aliased on xtlo
// (LDS 101KB -> 33.8KB, 1 -> 4 blocks/CU). k_qk: no atomics, 128 K-splits,
// 512-thr blocks, partials to ws (aliased with outb). New k_sred; k_softmax
// shuffle-based with 64 blocks.
// ---------------------------------------------------------------------------

typedef __attribute__((ext_vector_type(8))) short bf16x8;   // 8 bf16 (4 VGPR)
typedef __attribute__((ext_vector_type(4))) float f4;       // MFMA C/D

#define MFMA16(a, b, c) __builtin_amdgcn_mfma_f32_16x16x32_bf16(a, b, c, 0, 0, 0)

__device__ __forceinline__ unsigned short f2bf(float f) {  // RNE
  union { float f; unsigned u; } v; v.f = f;
  unsigned r = v.u + 0x7fffu + ((v.u >> 16) & 1u);
  return (unsigned short)(r >> 16);
}
__device__ __forceinline__ float bf2f(unsigned short h) {
  union { unsigned u; float f; } v; v.u = ((unsigned)h) << 16;
  return v.f;
}
__device__ __forceinline__ void splitf(float f, unsigned short &hi, unsigned short &lo) {
  unsigned short h = f2bf(f);
  hi = h; lo = f2bf(f - bf2f(h));
}

// truncation split of 8 floats -> hi/lo bf16x8 using v_perm packing (cheap).
__device__ __forceinline__ void split8t(float4 a, float4 b, bf16x8 &hi, bf16x8 &lo) {
  union { bf16x8 v; unsigned u[4]; } uh, ul;
  const unsigned* ua = (const unsigned*)&a;
  const unsigned* ub = (const unsigned*)&b;
  const float* fa = (const float*)&a;
  const float* fb = (const float*)&b;
#pragma unroll
  for (int e = 0; e < 2; ++e) {
    uh.u[e]     = __builtin_amdgcn_perm(ua[2*e+1], ua[2*e], 0x07060302u);
    uh.u[2 + e] = __builtin_amdgcn_perm(ub[2*e+1], ub[2*e], 0x07060302u);
    union { float f; unsigned u; } p0, p1, q0, q1;
    p0.u = ua[2*e] & 0xffff0000u;   p1.u = ua[2*e+1] & 0xffff0000u;
    p0.f = fa[2*e] - p0.f;          p1.f = fa[2*e+1] - p1.f;
    ul.u[e] = __builtin_amdgcn_perm(p1.u, p0.u, 0x07060302u);
    q0.u = ub[2*e] & 0xffff0000u;   q1.u = ub[2*e+1] & 0xffff0000u;
    q0.f = fb[2*e] - q0.f;          q1.f = fb[2*e+1] - q1.f;
    ul.u[2 + e] = __builtin_amdgcn_perm(q1.u, q0.u, 0x07060302u);
  }
  hi = uh.v; lo = ul.v;
}

// truncation-pack 8 floats -> bf16x8 (4 v_perm)
__device__ __forceinline__ bf16x8 pack8t(float4 a, float4 b) {
  union { bf16x8 v; unsigned u[4]; } r;
  const unsigned* ua = (const unsigned*)&a;
  const unsigned* ub = (const unsigned*)&b;
  r.u[0] = __builtin_amdgcn_perm(ua[1], ua[0], 0x07060302u);
  r.u[1] = __builtin_amdgcn_perm(ua[3], ua[2], 0x07060302u);
  r.u[2] = __builtin_amdgcn_perm(ub[1], ub[0], 0x07060302u);
  r.u[3] = __builtin_amdgcn_perm(ub[3], ub[2], 0x07060302u);
  return r.v;
}

// ---------------------------------------------------------------------------
// K0: precompute weight splits (reused by all conv blocks)
// ---------------------------------------------------------------------------
__global__ __launch_bounds__(256) void k_prep(
    const float* __restrict__ Wq, const float* __restrict__ Wk,
    const float* __restrict__ Wv, const float* __restrict__ Wu,
    unsigned short* __restrict__ wqh, unsigned short* __restrict__ wql,
    unsigned short* __restrict__ wkh, unsigned short* __restrict__ wkl,
    unsigned short* __restrict__ wvh, unsigned short* __restrict__ wuh) {
  const int i = blockIdx.x * 256 + threadIdx.x;  // 65536 total
  unsigned short h, lo2;
  splitf(Wq[i], h, lo2); wqh[i] = h; wql[i] = lo2;
  splitf(Wk[i], h, lo2); wkh[i] = h; wkl[i] = lo2;
  wvh[i] = f2bf(Wv[i]);
  wuh[i] = f2bf(Wu[i]);
}

// ---------------------------------------------------------------------------
// K1: fused QKV 1x1 conv.  Per block: 256 out-channels x 32 hw positions.
// LDS: xthi/xtlo (split x tile, transposed) 33.8KB; tbuf ALIASES xtlo
// (xtlo dead after K conv pass; V pass reads only xthi) -> 4 blocks/CU.
// ---------------------------------------------------------------------------
__global__ __launch_bounds__(256, 4) void k_qkv(
    const float* __restrict__ x,
    const unsigned short* __restrict__ wqh, const unsigned short* __restrict__ wql,
    const unsigned short* __restrict__ wkh, const unsigned short* __restrict__ wkl,
    const unsigned short* __restrict__ wvh,
    const float* __restrict__ bq, const float* __restrict__ bk,
    const float* __restrict__ bv,
    float* __restrict__ outQ, float* __restrict__ outKT, float* __restrict__ outVT,
    float* __restrict__ K2f) {
  const int pb = blockIdx.x, b = blockIdx.y;
  const int p0 = pb * 32;
  const int t = threadIdx.x;

  __shared__ __align__(16) unsigned short xthi[32][264];
  __shared__ __align__(16) unsigned short xtlo[32][264];  // aliased by tbuf
  float (*tbuf)[132] = reinterpret_cast<float (*)[132]>(&xtlo[0][0]);

  {  // stage x[b, :, p0..p0+31] transposed + split
    const int cp = t & 127;          // channel pair 2cp, 2cp+1
    const int hh = (t >> 7) * 16;    // position offset 0 / 16
    const float* r0 = x + ((size_t)b * 256 + 2 * cp) * 16384 + p0 + hh;
    const float* r1 = r0 + 16384;
#pragma unroll
    for (int q = 0; q < 4; ++q) {
      float4 v0 = *(const float4*)(r0 + 4 * q);
      float4 v1 = *(const float4*)(r1 + 4 * q);
      const unsigned* u0 = (const unsigned*)&v0;
      const unsigned* u1 = (const unsigned*)&v1;
      const float* f0 = (const float*)&v0;
      const float* f1 = (const float*)&v1;
#pragma unroll
      for (int e = 0; e < 4; ++e) {
        const int p = hh + 4 * q + e;
        *(unsigned*)&xthi[p][2 * cp] = __builtin_amdgcn_perm(u1[e], u0[e], 0x07060302u);
        union { float f; unsigned u; } l0, l1;
        l0.u = u0[e] & 0xffff0000u;  l1.u = u1[e] & 0xffff0000u;
        l0.f = f0[e] - l0.f;         l1.f = f1[e] - l1.f;
        *(unsigned*)&xtlo[p][2 * cp] = __builtin_amdgcn_perm(l1.u, l0.u, 0x07060302u);
      }
    }
  }
  __syncthreads();

  const int wv = t >> 6, l = t & 63;
  const int lr = l & 15, lkq = l >> 4, lk = lkq * 8;
  const size_t ob = (size_t)b * 4194304;
  const f4 fz = {0.f, 0.f, 0.f, 0.f};
  f4 acc[4][2];

#define CONV_PASS(WHI, WLO, SPLIT)                                        \
  {                                                                       \
    _Pragma("unroll") for (int mt = 0; mt < 4; ++mt)                      \
    _Pragma("unroll") for (int nt = 0; nt < 2; ++nt) acc[mt][nt] = fz;    \
    _Pragma("unroll 1") for (int kk = 0; kk < 8; ++kk) {                  \
      const int c0 = kk * 32 + lk;                                        \
      bf16x8 ahi[4], alo[4], bhi[2], blo[2];                              \
      _Pragma("unroll") for (int mt = 0; mt < 4; ++mt) {                  \
        const int o = wv * 64 + mt * 16 + lr;                             \
        ahi[mt] = *(const bf16x8*)(WHI + o * 256 + c0);                   \
        if (SPLIT) alo[mt] = *(const bf16x8*)(WLO + o * 256 + c0);        \
      }                                                                   \
      _Pragma("unroll") for (int nt = 0; nt < 2; ++nt) {                  \
        bhi[nt] = *(const bf16x8*)&xthi[nt * 16 + lr][c0];                \
        if (SPLIT) blo[nt] = *(const bf16x8*)&xtlo[nt * 16 + lr][c0];     \
      }                                                                   \
      _Pragma("unroll") for (int mt = 0; mt < 4; ++mt)                    \
      _Pragma("unroll") for (int nt = 0; nt < 2; ++nt) {                  \
        acc[mt][nt] = MFMA16(ahi[mt], bhi[nt], acc[mt][nt]);              \
        if (SPLIT) {                                                      \
          acc[mt][nt] = MFMA16(ahi[mt], blo[nt], acc[mt][nt]);            \
          acc[mt][nt] = MFMA16(alo[mt], bhi[nt], acc[mt][nt]);            \
        }                                                                 \
      }                                                                   \
    }                                                                     \
  }

  // LDS transpose-out via tbuf (aliases xtlo): rows x_?w[b, par*16384+p, 0..127]
#define TRANSPOSE_OUT(DST)                                                   \
  _Pragma("unroll") for (int par = 0; par < 2; ++par) {                      \
    __syncthreads();                                                         \
    _Pragma("unroll") for (int mt = 0; mt < 4; ++mt)                         \
    _Pragma("unroll") for (int m = 0; m < 2; ++m) {                          \
      const int i = wv * 32 + mt * 8 + lkq * 2 + m;                          \
      const int e = par + 2 * m; /* o parity == e parity (base even) */      \
      _Pragma("unroll") for (int nt = 0; nt < 2; ++nt)                       \
        tbuf[nt * 16 + lr][i] = acc[mt][nt][e];                              \
    }                                                                        \
    __syncthreads();                                                         \
    {                                                                        \
      const int pr = t >> 3, c4 = (t & 7) * 16;                              \
      float* dst = DST + ob + (size_t)(par * 16384 + p0 + pr) * 128 + c4;    \
      _Pragma("unroll") for (int q2 = 0; q2 < 4; ++q2)                       \
        *(float4*)(dst + 4 * q2) = *(const float4*)&tbuf[pr][c4 + 4 * q2];   \
    }                                                                        \
  }

  // ---------------- Q (split precision, contiguous out) ----------------
  CONV_PASS(wqh, wql, 1)
  {
    const int rbase = wv * 64 + lkq * 4;
#pragma unroll
    for (int mt = 0; mt < 4; ++mt)
#pragma unroll
      for (int e = 0; e < 4; ++e) {
        const int o = rbase + mt * 16 + e;
        const float bb = bq[o];
#pragma unroll
        for (int nt = 0; nt < 2; ++nt)
          outQ[ob + (size_t)o * 16384 + (p0 + nt * 16 + lr)] =
              fmaxf(acc[mt][nt][e] + bb, 0.0f);
      }
  }

  // ---------------- K (split; contiguous ws copy + transposed) ----------
  CONV_PASS(wkh, wkl, 1)
  {
    const int rbase = wv * 64 + lkq * 4;
#pragma unroll
    for (int mt = 0; mt < 4; ++mt)
#pragma unroll
      for (int e = 0; e < 4; ++e) {
        const int o = rbase + mt * 16 + e;
        const float bb = bk[o];
#pragma unroll
        for (int nt = 0; nt < 2; ++nt) {
          const float v = fmaxf(acc[mt][nt][e] + bb, 0.0f);
          acc[mt][nt][e] = v;
          K2f[ob + (size_t)o * 16384 + (p0 + nt * 16 + lr)] = v;
        }
      }
  }
  TRANSPOSE_OUT(outKT)   // clobbers xtlo (dead) via tbuf

  // ---------------- V (plain bf16, reads only xthi; transposed out) -----
  CONV_PASS(wvh, wvh, 0)
  {
    const int rbase = wv * 64 + lkq * 4;
#pragma unroll
    for (int mt = 0; mt < 4; ++mt)
#pragma unroll
      for (int e = 0; e < 4; ++e) {
        const int o = rbase + mt * 16 + e;
        const float bb = bv[o];
#pragma unroll
        for (int nt = 0; nt < 2; ++nt)
          acc[mt][nt][e] = fmaxf(acc[mt][nt][e] + bb, 0.0f);
      }
  }
  TRANSPOSE_OUT(outVT)
#undef CONV_PASS
#undef TRANSPOSE_OUT
}

// ---------------------------------------------------------------------------
// K2: partial S = Q2 @ K2^T.  128 K-splits (range 256), 512-thr blocks:
// 8 wave-tiles of 64x32 cover the 128x128 output.  Plain stores (no atomics)
// to Spart[b][split][128][128].
// ---------------------------------------------------------------------------
__global__ __launch_bounds__(512, 4) void k_qk(
    const float* __restrict__ Q2, const float* __restrict__ K2f,
    float* __restrict__ Spart) {
  const int s = blockIdx.x, b = blockIdx.y;
  const int t = threadIdx.x;
  const int wvv = t >> 6, l = t & 63;
  const int wm = (wvv >> 2) * 64, wn = (wvv & 3) * 32;
  const int lr = l & 15, lkq = l >> 4, lk = lkq * 8;
  const size_t qb = (size_t)b * 4194304;
  const int jb = s * 256;
  const f4 fz = {0.f, 0.f, 0.f, 0.f};
  f4 acc[4][2];
#pragma unroll
  for (int mt = 0; mt < 4; ++mt)
#pragma unroll
    for (int nt = 0; nt < 2; ++nt) acc[mt][nt] = fz;

#pragma unroll 1
  for (int kk = 0; kk < 8; ++kk) {
    const int j = jb + kk * 32 + lk;
    bf16x8 ahi[4], alo[4], bhi[2], blo[2];
#pragma unroll
    for (int mt = 0; mt < 4; ++mt) {
      const float* r = Q2 + qb + (size_t)(wm + mt * 16 + lr) * 32768 + j;
      split8t(*(const float4*)r, *(const float4*)(r + 4), ahi[mt], alo[mt]);
    }
#pragma unroll
    for (int nt = 0; nt < 2; ++nt) {
      const float* r = K2f + qb + (size_t)(wn + nt * 16 + lr) * 32768 + j;
      split8t(*(const float4*)r, *(const float4*)(r + 4), bhi[nt], blo[nt]);
    }
#pragma unroll
    for (int mt = 0; mt < 4; ++mt)
#pragma unroll
      for (int nt = 0; nt < 2; ++nt) {
        acc[mt][nt] = MFMA16(ahi[mt], bhi[nt], acc[mt][nt]);
        acc[mt][nt] = MFMA16(ahi[mt], blo[nt], acc[mt][nt]);
        acc[mt][nt] = MFMA16(alo[mt], bhi[nt], acc[mt][nt]);
      }
  }
  float* out = Spart + ((size_t)(b * 128 + s)) * 16384;
#pragma unroll
  for (int mt = 0; mt < 4; ++mt)
#pragma unroll
    for (int e = 0; e < 4; ++e) {
      const int i1 = wm + mt * 16 + lkq * 4 + e;
#pragma unroll
      for (int nt = 0; nt < 2; ++nt)
        out[i1 * 128 + (wn + nt * 16 + lr)] = acc[mt][nt][e];
    }
}

// ---------------------------------------------------------------------------
// K2b: reduce the 128 partials -> S[b][128][128]
// ---------------------------------------------------------------------------
__global__ __launch_bounds__(256) void k_sred(
    const float* __restrict__ Spart, float* __restrict__ S) {
  const int e = blockIdx.x * 256 + threadIdx.x;  // 0..16383
  const int b = blockIdx.y;
  const float* p = Spart + (size_t)b * 128 * 16384 + e;
  float s0 = 0.f, s1 = 0.f, s2 = 0.f, s3 = 0.f;
#pragma unroll 4
  for (int s = 0; s < 128; s += 4) {
    s0 += p[(size_t)s * 16384];
    s1 += p[(size_t)(s + 1) * 16384];
    s2 += p[(size_t)(s + 2) * 16384];
    s3 += p[(size_t)(s + 3) * 16384];
  }
  S[b * 16384 + e] = (s0 + s1) + (s2 + s3);
}

// ---------------------------------------------------------------------------
// K3: softmax over axis i1 (per column i2).  64 blocks, 8 cols each,
// 32-lane shuffle reductions.  Writes attn fp32, gamma, bf16 attn^T * gamma.
// ---------------------------------------------------------------------------
__global__ __launch_bounds__(256) void k_softmax(
    const float* __restrict__ S, const float* __restrict__ gin,
    float* __restrict__ attnO, float* __restrict__ gammaO,
    unsigned short* __restrict__ attnTg) {
  const int cb = blockIdx.x, b = blockIdx.y;
  const int t = threadIdx.x;
  const int col = cb * 8 + (t >> 5);
  const int r = t & 31;
  const float* Sb = S + b * 16384;
  float v[4];
#pragma unroll
  for (int j = 0; j < 4; ++j) v[j] = Sb[(r + 32 * j) * 128 + col];
  float m = fmaxf(fmaxf(v[0], v[1]), fmaxf(v[2], v[3]));
#pragma unroll
  for (int k = 16; k >= 1; k >>= 1) m = fmaxf(m, __shfl_xor(m, k, 32));
  float sum = 0.f;
#pragma unroll
  for (int j = 0; j < 4; ++j) { v[j] = expf(v[j] - m); sum += v[j]; }
#pragma unroll
  for (int k = 16; k >= 1; k >>= 1) sum += __shfl_xor(sum, k, 32);
  const float inv = 1.0f / sum;
  const float g = gin[0];
#pragma unroll
  for (int j = 0; j < 4; ++j) {
    const float p2 = v[j] * inv;
    attnO[b * 16384 + (r + 32 * j) * 128 + col] = p2;
    attnTg[(size_t)b * 16384 + (size_t)col * 128 + (r + 32 * j)] = f2bf(p2 * g);
  }
  if (b == 0 && cb == 0 && t == 0) gammaO[0] = gin[0];
}

// ---------------------------------------------------------------------------
// K4: out1 = V^T @ attn (gamma folded in attnTg), bf16 out to ws.
// ---------------------------------------------------------------------------
__global__ __launch_bounds__(256) void k_pv(
    const float* __restrict__ VT, const unsigned short* __restrict__ attnTg,
    unsigned short* __restrict__ outb) {
  const int jblk = blockIdx.x, b = blockIdx.y;
  const int t = threadIdx.x;
  const int wvv = t >> 6, l = t & 63;
  const int lr = l & 15, lkq = l >> 4, lk = lkq * 8;
  const size_t vb = (size_t)b * 4194304;
  const int j0 = jblk * 256 + wvv * 64;
  const f4 fz = {0.f, 0.f, 0.f, 0.f};
  f4 acc[4][8];
#pragma unroll
  for (int mt = 0; mt < 4; ++mt)
#pragma unroll
    for (int nt = 0; nt < 8; ++nt) acc[mt][nt] = fz;

#pragma unroll
  for (int kk = 0; kk < 4; ++kk) {
    const int k0 = kk * 32 + lk;
    bf16x8 av[4], bt[8];
#pragma unroll
    for (int mt = 0; mt < 4; ++mt) {
      const float* r = VT + vb + (size_t)(j0 + mt * 16 + lr) * 128 + k0;
      av[mt] = pack8t(*(const float4*)r, *(const float4*)(r + 4));
    }
#pragma unroll
    for (int nt = 0; nt < 8; ++nt)
      bt[nt] = *(const bf16x8*)(attnTg + (size_t)b * 16384 +
                                (size_t)(nt * 16 + lr) * 128 + k0);
#pragma unroll
    for (int mt = 0; mt < 4; ++mt)
#pragma unroll
      for (int nt = 0; nt < 8; ++nt)
        acc[mt][nt] = MFMA16(av[mt], bt[nt], acc[mt][nt]);
  }
#pragma unroll
  for (int mt = 0; mt < 4; ++mt)
#pragma unroll
    for (int e = 0; e < 4; ++e) {
      const int j = j0 + mt * 16 + lkq * 4 + e;
#pragma unroll
      for (int nt = 0; nt < 8; ++nt)
        outb[vb + (size_t)j * 128 + (nt * 16 + lr)] = f2bf(acc[mt][nt][e]);
    }
}

// ---------------------------------------------------------------------------
// K5: out_w = Wu @ out + bu, plain bf16 MFMA, fp32 out.
// ---------------------------------------------------------------------------
__global__ __launch_bounds__(256) void k_up(
    const unsigned short* __restrict__ outb, const unsigned short* __restrict__ wuh,
    const float* __restrict__ bu, float* __restrict__ outw) {
  const int pb = blockIdx.x, b = blockIdx.y;
  const int p0 = pb * 64;
  const int t = threadIdx.x;
  __shared__ unsigned short ot[64][264];
  {
    const int cp = t & 127;
    const int ph = (t >> 7) * 32;
    const unsigned short* row0 = outb + ((size_t)b * 256 + 2 * cp) * 16384 + p0 + ph;
    const unsigned* r0 = (const unsigned*)row0;
    const unsigned* r1 = (const unsigned*)(row0 + 16384);
#pragma unroll
    for (int k = 0; k < 16; ++k) {
      const unsigned a0 = r0[k], a1 = r1[k];
      const int p = ph + 2 * k;
      *(unsigned*)&ot[p][2 * cp] = (a0 & 0xffffu) | (a1 << 16);
      *(unsigned*)&ot[p + 1][2 * cp] = (a0 >> 16) | (a1 & 0xffff0000u);
    }
  }
  __syncthreads();
  const int wv = t >> 6, l = t & 63;
  const int lr = l & 15, lkq = l >> 4, lk = lkq * 8;
  const f4 fz = {0.f, 0.f, 0.f, 0.f};
  f4 acc[4][4];
#pragma unroll
  for (int mt = 0; mt < 4; ++mt)
#pragma unroll
    for (int nt = 0; nt < 4; ++nt) acc[mt][nt] = fz;

#pragma unroll 1
  for (int kk = 0; kk < 8; ++kk) {
    const int c0 = kk * 32 + lk;
    bf16x8 a[4], bt[4];
#pragma unroll
    for (int mt = 0; mt < 4; ++mt)
      a[mt] = *(const bf16x8*)(wuh + (wv * 64 + mt * 16 + lr) * 256 + c0);
#pragma unroll
    for (int nt = 0; nt < 4; ++nt)
      bt[nt] = *(const bf16x8*)&ot[nt * 16 + lr][c0];
#pragma unroll
    for (int mt = 0; mt < 4; ++mt)
#pragma unroll
      for (int nt = 0; nt < 4; ++nt)
        acc[mt][nt] = MFMA16(a[mt], bt[nt], acc[mt][nt]);
  }
  const size_t ob2 = (size_t)b * 4194304;
  const int rbase = wv * 64 + lkq * 4;
#pragma unroll
  for (int mt = 0; mt < 4; ++mt)
#pragma unroll
    for (int e = 0; e < 4; ++e) {
      const int o = rbase + mt * 16 + e;
      const float bb = bu[o];
#pragma unroll
      for (int nt = 0; nt < 4; ++nt)
        outw[ob2 + (size_t)o * 16384 + (p0 + nt * 16 + lr)] = acc[mt][nt][e] + bb;
    }
}

// ---------------------------------------------------------------------------
extern "C" void kernel_launch(void* const* d_in, const int* in_sizes, int n_in,
                              void* d_out, int out_size, void* d_ws, size_t ws_size,
                              hipStream_t stream) {
  (void)in_sizes; (void)n_in; (void)out_size; (void)ws_size;
  const float* x  = (const float*)d_in[0];
  const float* Wq = (const float*)d_in[1];
  const float* bq = (const float*)d_in[2];
  const float* Wk = (const float*)d_in[3];
  const float* bk = (const float*)d_in[4];
  const float* Wv = (const float*)d_in[5];
  const float* bv = (const float*)d_in[6];
  const float* Wu = (const float*)d_in[7];
  const float* bu = (const float*)d_in[8];
  const float* gm = (const float*)d_in[9];

  float* dout   = (float*)d_out;
  float* outw   = dout;                 // [4,256,128,128]
  float* outQ   = dout + 16777216;      // x_Qw  (contiguous conv out)
  float* outKT  = dout + 33554432;      // x_Kw  (transposed)
  float* outVT  = dout + 50331648;      // x_Vw  (transposed)
  float* gammaO = dout + 67108864;      // gamma
  float* attnO  = dout + 67108865;      // attn [4,128,128]

  // ws layout (Spart and outb ALIAS: disjoint lifetimes, stream-ordered)
  char* wsb = (char*)d_ws;
  float* K2f   = (float*)(wsb);                                // 64 MiB
  float* Spart = (float*)(wsb + 67108864);                     // 32 MiB (k_qk -> k_sred)
  unsigned short* outb = (unsigned short*)(wsb + 67108864);    // 32 MiB (k_pv -> k_up)
  float* S     = (float*)(wsb + 100663296);                    // 256 KiB
  unsigned short* attnTg = (unsigned short*)(wsb + 100925440); // 128 KiB
  unsigned short* wqh = (unsigned short*)(wsb + 101056512);
  unsigned short* wql = wqh + 65536;
  unsigned short* wkh = wql + 65536;
  unsigned short* wkl = wkh + 65536;
  unsigned short* wvh = wkl + 65536;
  unsigned short* wuh = wvh + 65536;

  k_prep<<<dim3(256), dim3(256), 0, stream>>>(Wq, Wk, Wv, Wu,
                                              wqh, wql, wkh, wkl, wvh, wuh);
  k_qkv<<<dim3(512, 4), dim3(256), 0, stream>>>(x, wqh, wql, wkh, wkl, wvh,
                                                bq, bk, bv,
                                                outQ, outKT, outVT, K2f);
  k_qk<<<dim3(128, 4), dim3(512), 0, stream>>>(outQ, K2f, Spart);
  k_sred<<<dim3(64, 4), dim3(256), 0, stream>>>(Spart, S);
  k_softmax<<<dim3(16, 4), dim3(256), 0, stream>>>(S, gm, attnO, gammaO, attnTg);
  k_pv<<<dim3(128, 4), dim3(256), 0, stream>>>(outVT, attnTg, outb);
  k_up<<<dim3(256, 4), dim3(256), 0, stream>>>(outb, wuh, bu, outw);
}